// Round 1
// baseline (668.341 us; speedup 1.0000x reference)
//
#include <hip/hip_runtime.h>

#define FIN 78
#define CDIM 128
#define HEADS 10
#define HC 1280
#define GRAPHS 64

// ---------------- init ----------------
__global__ void init_kernel(unsigned* counts, unsigned* cursor, unsigned* pooled_u, int N) {
    int t = blockIdx.x * 256 + threadIdx.x;
    if (t < N) { counts[t] = 0u; cursor[t] = 0u; }
    if (t < GRAPHS * CDIM) pooled_u[t] = 0x007FFFFFu;  // enc(-inf)
}

// ---------------- tiled fp32 GEMM: C[M,N] = A[M,K] @ B[K,N] ----------------
template<int BM, int BN, int BK, int TM, int TN>
__global__ void gemm_kernel(const float* __restrict__ A, const float* __restrict__ B,
                            float* __restrict__ Cmat, int M, int N, int K) {
    __shared__ float As[BK][BM];
    __shared__ float Bs[BK][BN];
    constexpr int NTX = BN / TN;
    constexpr int NTY = BM / TM;
    static_assert(NTX * NTY == 256, "256 threads");
    const int tid = threadIdx.x;
    const int tx = tid % NTX, ty = tid / NTX;
    const int m0 = blockIdx.x * BM;
    const int n0 = blockIdx.y * BN;

    float acc[TM][TN] = {};

    for (int k0 = 0; k0 < K; k0 += BK) {
        for (int idx = tid; idx < BM * BK; idx += 256) {
            int i = idx / BK, k = idx % BK;
            int gm = m0 + i, gk = k0 + k;
            float v = (gm < M && gk < K) ? A[(size_t)gm * K + gk] : 0.f;
            As[k][i] = v;
        }
        for (int idx = tid; idx < BK * BN; idx += 256) {
            int j = idx % BN, k = idx / BN;
            int gk = k0 + k;
            float v = (gk < K) ? B[(size_t)gk * N + n0 + j] : 0.f;
            Bs[k][j] = v;
        }
        __syncthreads();
        #pragma unroll
        for (int k = 0; k < BK; ++k) {
            float a_r[TM], b_r[TN];
            #pragma unroll
            for (int t = 0; t < TM; ++t) a_r[t] = As[k][ty * TM + t];
            #pragma unroll
            for (int u = 0; u < TN; ++u) b_r[u] = Bs[k][tx * TN + u];
            #pragma unroll
            for (int t = 0; t < TM; ++t)
                #pragma unroll
                for (int u = 0; u < TN; ++u)
                    acc[t][u] += a_r[t] * b_r[u];
        }
        __syncthreads();
    }
    #pragma unroll
    for (int t = 0; t < TM; ++t) {
        int gm = m0 + ty * TM + t;
        if (gm < M) {
            #pragma unroll
            for (int u = 0; u < TN; ++u)
                Cmat[(size_t)gm * N + n0 + tx * TN + u] = acc[t][u];
        }
    }
}

// ---------------- attention scores, layer 1 (10 heads) ----------------
__global__ void scores1_kernel(const float* __restrict__ h1p,
                               const float* __restrict__ asrc, const float* __restrict__ adst,
                               float* __restrict__ as1, float* __restrict__ ad1, int N) {
    int lane = threadIdx.x & 63;
    int w = threadIdx.x >> 6;
    int n = blockIdx.x * 4 + w;
    if (n >= N) return;
    const float* hrow = h1p + (size_t)n * HC;
    for (int h = 0; h < HEADS; ++h) {
        int c0 = h * CDIM + lane;
        float hv0 = hrow[c0], hv1 = hrow[c0 + 64];
        float ps = hv0 * asrc[c0] + hv1 * asrc[c0 + 64];
        float pd = hv0 * adst[c0] + hv1 * adst[c0 + 64];
        #pragma unroll
        for (int off = 32; off; off >>= 1) {
            ps += __shfl_xor(ps, off);
            pd += __shfl_xor(pd, off);
        }
        if (lane == 0) { as1[n * HEADS + h] = ps; ad1[n * HEADS + h] = pd; }
    }
}

// ---------------- attention scores, layer 2 (1 head) ----------------
__global__ void scores2_kernel(const float* __restrict__ h2p,
                               const float* __restrict__ asrc, const float* __restrict__ adst,
                               float* __restrict__ as2, float* __restrict__ ad2, int N) {
    int lane = threadIdx.x & 63;
    int w = threadIdx.x >> 6;
    int n = blockIdx.x * 4 + w;
    if (n >= N) return;
    const float* hrow = h2p + (size_t)n * CDIM;
    float hv0 = hrow[lane], hv1 = hrow[lane + 64];
    float ps = hv0 * asrc[lane] + hv1 * asrc[lane + 64];
    float pd = hv0 * adst[lane] + hv1 * adst[lane + 64];
    #pragma unroll
    for (int off = 32; off; off >>= 1) {
        ps += __shfl_xor(ps, off);
        pd += __shfl_xor(pd, off);
    }
    if (lane == 0) { as2[n] = ps; ad2[n] = pd; }
}

// ---------------- CSR build ----------------
__global__ void hist_kernel(const int* __restrict__ ei, int E, int N, unsigned* counts) {
    int e = blockIdx.x * 256 + threadIdx.x;
    int Et = E + N;
    if (e >= Et) return;
    int d = (e < E) ? ei[E + e] : (e - E);
    atomicAdd(&counts[d], 1u);
}

__global__ void scan_kernel(const unsigned* __restrict__ counts, unsigned* __restrict__ offsets, int n) {
    __shared__ unsigned part[1024];
    int t = threadIdx.x;
    int chunk = (n + 1023) / 1024;
    int lo = t * chunk, hi = min(lo + chunk, n);
    unsigned s = 0;
    for (int i = lo; i < hi; ++i) s += counts[i];
    part[t] = s;
    __syncthreads();
    for (int d = 1; d < 1024; d <<= 1) {
        unsigned v = (t >= d) ? part[t - d] : 0u;
        __syncthreads();
        part[t] += v;
        __syncthreads();
    }
    unsigned base = (t == 0) ? 0u : part[t - 1];
    for (int i = lo; i < hi; ++i) { offsets[i] = base; base += counts[i]; }
    if (t == 1023) offsets[n] = part[1023];
}

__global__ void scatter_kernel(const int* __restrict__ ei, int E, int N,
                               const unsigned* __restrict__ offsets, unsigned* cursor,
                               int* __restrict__ csr_src, int* __restrict__ csr_eid) {
    int e = blockIdx.x * 256 + threadIdx.x;
    int Et = E + N;
    if (e >= Et) return;
    int s, d;
    if (e < E) { s = ei[e]; d = ei[E + e]; } else { s = e - E; d = e - E; }
    unsigned pos = offsets[d] + atomicAdd(&cursor[d], 1u);
    csr_src[pos] = s;
    csr_eid[pos] = e;
}

// ---------------- segment softmax, layer 1: writes alpha1 into d_out ----------------
__global__ void softmax1_kernel(const unsigned* __restrict__ offsets,
                                const int* __restrict__ csr_src, const int* __restrict__ csr_eid,
                                const float* __restrict__ as1, const float* __restrict__ ad1,
                                float* __restrict__ alpha_out, int N) {
    int t = blockIdx.x * 256 + threadIdx.x;
    if (t >= N * HEADS) return;
    int n = t / HEADS, h = t % HEADS;
    unsigned p0 = offsets[n], p1 = offsets[n + 1];
    float adn = ad1[n * HEADS + h];
    float m = -INFINITY;
    for (unsigned p = p0; p < p1; ++p) {
        float e = as1[csr_src[p] * HEADS + h] + adn;
        e = (e >= 0.f) ? e : 0.2f * e;
        m = fmaxf(m, e);
    }
    float den = 0.f;
    for (unsigned p = p0; p < p1; ++p) {
        float e = as1[csr_src[p] * HEADS + h] + adn;
        e = (e >= 0.f) ? e : 0.2f * e;
        den += __expf(e - m);
    }
    float inv = 1.f / (den + 1e-16f);
    for (unsigned p = p0; p < p1; ++p) {
        float e = as1[csr_src[p] * HEADS + h] + adn;
        e = (e >= 0.f) ? e : 0.2f * e;
        alpha_out[(size_t)csr_eid[p] * HEADS + h] = __expf(e - m) * inv;
    }
}

// ---------------- segment softmax, layer 2 (alpha in CSR order) ----------------
__global__ void softmax2_kernel(const unsigned* __restrict__ offsets,
                                const int* __restrict__ csr_src,
                                const float* __restrict__ as2, const float* __restrict__ ad2,
                                float* __restrict__ alpha2, int N) {
    int n = blockIdx.x * 256 + threadIdx.x;
    if (n >= N) return;
    unsigned p0 = offsets[n], p1 = offsets[n + 1];
    float adn = ad2[n];
    float m = -INFINITY;
    for (unsigned p = p0; p < p1; ++p) {
        float e = as2[csr_src[p]] + adn;
        e = (e >= 0.f) ? e : 0.2f * e;
        m = fmaxf(m, e);
    }
    float den = 0.f;
    for (unsigned p = p0; p < p1; ++p) {
        float e = as2[csr_src[p]] + adn;
        e = (e >= 0.f) ? e : 0.2f * e;
        den += __expf(e - m);
    }
    float inv = 1.f / (den + 1e-16f);
    for (unsigned p = p0; p < p1; ++p) {
        float e = as2[csr_src[p]] + adn;
        e = (e >= 0.f) ? e : 0.2f * e;
        alpha2[p] = __expf(e - m) * inv;
    }
}

// ---------------- aggregation layer 1 + elu: one block (256t) per node ----------------
__global__ void agg1_kernel(const unsigned* __restrict__ offsets,
                            const int* __restrict__ csr_src, const int* __restrict__ csr_eid,
                            const float* __restrict__ alpha_out, const float* __restrict__ h1p,
                            const float* __restrict__ b1, float* __restrict__ h1, int N) {
    __shared__ float a_lds[64 * HEADS];
    __shared__ int s_lds[64];
    int n = blockIdx.x;
    unsigned p0 = offsets[n], p1 = offsets[n + 1];
    int tid = threadIdx.x;
    float acc[5] = {0.f, 0.f, 0.f, 0.f, 0.f};
    for (unsigned base = p0; base < p1; base += 64) {
        int cnt = (int)min(64u, p1 - base);
        for (int idx = tid; idx < cnt * HEADS; idx += 256) {
            int j = idx / HEADS, h = idx % HEADS;
            a_lds[idx] = alpha_out[(size_t)csr_eid[base + j] * HEADS + h];
        }
        for (int idx = tid; idx < cnt; idx += 256) s_lds[idx] = csr_src[base + idx];
        __syncthreads();
        for (int j = 0; j < cnt; ++j) {
            const float* hrow = h1p + (size_t)s_lds[j] * HC;
            #pragma unroll
            for (int r = 0; r < 5; ++r) {
                int cc = tid + r * 256;
                acc[r] += hrow[cc] * a_lds[j * HEADS + (cc >> 7)];
            }
        }
        __syncthreads();
    }
    #pragma unroll
    for (int r = 0; r < 5; ++r) {
        int cc = tid + r * 256;
        float v = acc[r] + b1[cc];
        h1[(size_t)n * HC + cc] = (v > 0.f) ? v : expm1f(v);
    }
}

// ---------------- aggregation layer 2 + elu: one block (128t) per node ----------------
__global__ void agg2_kernel(const unsigned* __restrict__ offsets,
                            const int* __restrict__ csr_src, const float* __restrict__ alpha2,
                            const float* __restrict__ h2p, const float* __restrict__ b2,
                            float* __restrict__ h2, int N) {
    int n = blockIdx.x;
    int c = threadIdx.x;
    unsigned p0 = offsets[n], p1 = offsets[n + 1];
    float acc = 0.f;
    for (unsigned p = p0; p < p1; ++p) {
        acc += h2p[(size_t)csr_src[p] * CDIM + c] * alpha2[p];
    }
    float v = acc + b2[c];
    h2[(size_t)n * CDIM + c] = (v > 0.f) ? v : expm1f(v);
}

// ---------------- pooling: monotone-uint atomicMax ----------------
__device__ __forceinline__ unsigned enc_f(float f) {
    unsigned b = __float_as_uint(f);
    return (b & 0x80000000u) ? ~b : (b | 0x80000000u);
}
__device__ __forceinline__ float dec_f(unsigned k) {
    return (k & 0x80000000u) ? __uint_as_float(k & 0x7FFFFFFFu) : __uint_as_float(~k);
}

__global__ void pool_kernel(const float* __restrict__ h2, const int* __restrict__ batch,
                            unsigned* __restrict__ pooled_u, int N) {
    int t = blockIdx.x * 256 + threadIdx.x;
    if (t >= N * CDIM) return;
    int n = t >> 7, c = t & 127;
    atomicMax(&pooled_u[batch[n] * CDIM + c], enc_f(h2[t]));
}

__global__ void pool_write_kernel(const unsigned* __restrict__ pooled_u, float* __restrict__ out) {
    int t = blockIdx.x * 256 + threadIdx.x;
    if (t < GRAPHS * CDIM) out[t] = dec_f(pooled_u[t]);
}

extern "C" void kernel_launch(void* const* d_in, const int* in_sizes, int n_in,
                              void* d_out, int out_size, void* d_ws, size_t ws_size,
                              hipStream_t stream) {
    const float* x     = (const float*)d_in[0];
    const int*   ei    = (const int*)d_in[1];
    const int*   batch = (const int*)d_in[2];
    const float* W1    = (const float*)d_in[3];
    const float* asrc1 = (const float*)d_in[4];
    const float* adst1 = (const float*)d_in[5];
    const float* b1    = (const float*)d_in[6];
    const float* W2    = (const float*)d_in[7];
    const float* asrc2 = (const float*)d_in[8];
    const float* adst2 = (const float*)d_in[9];
    const float* b2    = (const float*)d_in[10];
    float* out = (float*)d_out;

    const int N  = in_sizes[0] / FIN;
    const int E  = in_sizes[1] / 2;
    const int Et = E + N;

    char* w = (char*)d_ws;
    auto alloc = [&](size_t nbytes) {
        char* p = w;
        w += (nbytes + 255) & ~(size_t)255;
        return p;
    };
    float* h1p      = (float*)alloc((size_t)N * HC * 4);
    float* h1       = (float*)alloc((size_t)N * HC * 4);
    float* h2p      = (float*)alloc((size_t)N * CDIM * 4);
    float* h2       = (float*)alloc((size_t)N * CDIM * 4);
    float* as1      = (float*)alloc((size_t)N * HEADS * 4);
    float* ad1      = (float*)alloc((size_t)N * HEADS * 4);
    float* as2      = (float*)alloc((size_t)N * 4);
    float* ad2      = (float*)alloc((size_t)N * 4);
    float* alpha2   = (float*)alloc((size_t)Et * 4);
    unsigned* counts  = (unsigned*)alloc((size_t)N * 4);
    unsigned* cursor  = (unsigned*)alloc((size_t)N * 4);
    unsigned* offsets = (unsigned*)alloc((size_t)(N + 1) * 4);
    int* csr_src = (int*)alloc((size_t)Et * 4);
    int* csr_eid = (int*)alloc((size_t)Et * 4);
    unsigned* pooled_u = (unsigned*)alloc((size_t)GRAPHS * CDIM * 4);

    float* alpha_out = out + GRAPHS * CDIM;  // alpha1 region of d_out

    init_kernel<<<(N + 255) / 256, 256, 0, stream>>>(counts, cursor, pooled_u, N);

    // layer-1 GEMM: [N,78] @ [78,1280]
    gemm_kernel<64, 128, 26, 4, 8><<<dim3((N + 63) / 64, HC / 128), 256, 0, stream>>>(
        x, W1, h1p, N, HC, FIN);
    scores1_kernel<<<(N + 3) / 4, 256, 0, stream>>>(h1p, asrc1, adst1, as1, ad1, N);

    // CSR by dst
    hist_kernel<<<(Et + 255) / 256, 256, 0, stream>>>(ei, E, N, counts);
    scan_kernel<<<1, 1024, 0, stream>>>(counts, offsets, N);
    scatter_kernel<<<(Et + 255) / 256, 256, 0, stream>>>(ei, E, N, offsets, cursor, csr_src, csr_eid);

    softmax1_kernel<<<(N * HEADS + 255) / 256, 256, 0, stream>>>(
        offsets, csr_src, csr_eid, as1, ad1, alpha_out, N);
    agg1_kernel<<<N, 256, 0, stream>>>(offsets, csr_src, csr_eid, alpha_out, h1p, b1, h1, N);

    // layer-2 GEMM: [N,1280] @ [1280,128]
    gemm_kernel<32, 128, 32, 2, 8><<<dim3((N + 31) / 32, 1), 256, 0, stream>>>(
        h1, W2, h2p, N, CDIM, HC);
    scores2_kernel<<<(N + 3) / 4, 256, 0, stream>>>(h2p, asrc2, adst2, as2, ad2, N);
    softmax2_kernel<<<(N + 255) / 256, 256, 0, stream>>>(offsets, csr_src, as2, ad2, alpha2, N);
    agg2_kernel<<<N, 128, 0, stream>>>(offsets, csr_src, alpha2, h2p, b2, h2, N);

    pool_kernel<<<(N * CDIM + 255) / 256, 256, 0, stream>>>(h2, batch, pooled_u, N);
    pool_write_kernel<<<(GRAPHS * CDIM + 255) / 256, 256, 0, stream>>>(pooled_u, out);
}

// Round 2
// 416.303 us; speedup vs baseline: 1.6054x; 1.6054x over previous
//
#include <hip/hip_runtime.h>
#include <hip/hip_bf16.h>

#define FIN 78
#define CDIM 128
#define HEADS 10
#define HC 1280
#define GRAPHS 64

typedef __bf16 bf16x8 __attribute__((ext_vector_type(8)));
typedef float f32x4 __attribute__((ext_vector_type(4)));

// ---------------- init ----------------
__global__ void init_kernel(unsigned* counts, unsigned* cursor, unsigned* pooled_u, int N) {
    int t = blockIdx.x * 256 + threadIdx.x;
    if (t < N) { counts[t] = 0u; cursor[t] = 0u; }
    if (t < GRAPHS * CDIM) pooled_u[t] = 0x007FFFFFu;  // enc(-inf)
}

// ---------------- tiled fp32 GEMM (layer 1): C[M,N] = A[M,K] @ B[K,N] ----------------
template<int BM, int BN, int BK, int TM, int TN>
__global__ void gemm_kernel(const float* __restrict__ A, const float* __restrict__ B,
                            float* __restrict__ Cmat, int M, int N, int K) {
    __shared__ float As[BK][BM];
    __shared__ float Bs[BK][BN];
    constexpr int NTX = BN / TN;
    constexpr int NTY = BM / TM;
    static_assert(NTX * NTY == 256, "256 threads");
    const int tid = threadIdx.x;
    const int tx = tid % NTX, ty = tid / NTX;
    const int m0 = blockIdx.x * BM;
    const int n0 = blockIdx.y * BN;

    float acc[TM][TN] = {};

    for (int k0 = 0; k0 < K; k0 += BK) {
        for (int idx = tid; idx < BM * BK; idx += 256) {
            int i = idx / BK, k = idx % BK;
            int gm = m0 + i, gk = k0 + k;
            float v = (gm < M && gk < K) ? A[(size_t)gm * K + gk] : 0.f;
            As[k][i] = v;
        }
        for (int idx = tid; idx < BK * BN; idx += 256) {
            int j = idx % BN, k = idx / BN;
            int gk = k0 + k;
            float v = (gk < K) ? B[(size_t)gk * N + n0 + j] : 0.f;
            Bs[k][j] = v;
        }
        __syncthreads();
        #pragma unroll
        for (int k = 0; k < BK; ++k) {
            float a_r[TM], b_r[TN];
            #pragma unroll
            for (int t = 0; t < TM; ++t) a_r[t] = As[k][ty * TM + t];
            #pragma unroll
            for (int u = 0; u < TN; ++u) b_r[u] = Bs[k][tx * TN + u];
            #pragma unroll
            for (int t = 0; t < TM; ++t)
                #pragma unroll
                for (int u = 0; u < TN; ++u)
                    acc[t][u] += a_r[t] * b_r[u];
        }
        __syncthreads();
    }
    #pragma unroll
    for (int t = 0; t < TM; ++t) {
        int gm = m0 + ty * TM + t;
        if (gm < M) {
            #pragma unroll
            for (int u = 0; u < TN; ++u)
                Cmat[(size_t)gm * N + n0 + tx * TN + u] = acc[t][u];
        }
    }
}

// ---------------- W2 transpose + bf16 convert: W2t[n][k] = bf16(W2[k][n]) ----------------
__global__ void w2t_kernel(const float* __restrict__ W2, __bf16* __restrict__ W2t) {
    int t = blockIdx.x * 256 + threadIdx.x;
    if (t >= HC * CDIM) return;
    int k = t >> 7, n = t & 127;
    W2t[(size_t)n * HC + k] = (__bf16)W2[t];
}

// ---------------- layer-2 GEMM via bf16 MFMA: C[M,128] = A[M,1280] @ W2t^T ----------------
// A row-major bf16 [M,1280]; Bt row-major bf16 [128,1280]; C fp32 [M,128].
// Block = 256 threads = 4 waves in 2x2, each wave a 32x32 tile of a 64x64 block tile.
__global__ __launch_bounds__(256) void gemm2_mfma_kernel(
        const __bf16* __restrict__ A, const __bf16* __restrict__ Bt,
        float* __restrict__ C, int M) {
    constexpr int BK = 64;
    __shared__ __align__(16) __bf16 Alds[64][BK + 8];
    __shared__ __align__(16) __bf16 Blds[64][BK + 8];
    const int tid = threadIdx.x;
    const int wave = tid >> 6, lane = tid & 63;
    const int wr = wave >> 1, wc = wave & 1;
    const int m0 = blockIdx.x * 64;
    const int n0 = blockIdx.y * 64;

    const int kslot = (tid & 7) * 8;   // staging: 8 threads cover 64 k
    const int srow  = tid >> 3;        // staging row 0..31 (two passes)

    const int fl = lane & 15;          // fragment row/col within 16
    const int fh = lane >> 4;          // quad 0..3

    f32x4 acc[2][2] = {};

    for (int k0 = 0; k0 < HC; k0 += BK) {
        #pragma unroll
        for (int rp = 0; rp < 2; ++rp) {
            int r = srow + rp * 32;
            int gm = m0 + r;
            bf16x8 va = {};
            if (gm < M) va = *(const bf16x8*)(A + (size_t)gm * HC + k0 + kslot);
            *(bf16x8*)&Alds[r][kslot] = va;
            bf16x8 vb = *(const bf16x8*)(Bt + (size_t)(n0 + r) * HC + k0 + kslot);
            *(bf16x8*)&Blds[r][kslot] = vb;
        }
        __syncthreads();
        #pragma unroll
        for (int ks = 0; ks < BK; ks += 32) {
            bf16x8 a[2], b[2];
            #pragma unroll
            for (int t = 0; t < 2; ++t) {
                a[t] = *(const bf16x8*)&Alds[wr * 32 + t * 16 + fl][ks + fh * 8];
                b[t] = *(const bf16x8*)&Blds[wc * 32 + t * 16 + fl][ks + fh * 8];
            }
            #pragma unroll
            for (int i = 0; i < 2; ++i)
                #pragma unroll
                for (int j = 0; j < 2; ++j)
                    acc[i][j] = __builtin_amdgcn_mfma_f32_16x16x32_bf16(a[i], b[j], acc[i][j], 0, 0, 0);
        }
        __syncthreads();
    }
    #pragma unroll
    for (int i = 0; i < 2; ++i) {
        #pragma unroll
        for (int j = 0; j < 2; ++j) {
            #pragma unroll
            for (int r = 0; r < 4; ++r) {
                int gm = m0 + wr * 32 + i * 16 + fh * 4 + r;
                if (gm < M) {
                    int gn = n0 + wc * 32 + j * 16 + fl;
                    C[(size_t)gm * CDIM + gn] = acc[i][j][r];
                }
            }
        }
    }
}

// ---------------- attention scores, layer 1 (10 heads) ----------------
__global__ void scores1_kernel(const float* __restrict__ h1p,
                               const float* __restrict__ asrc, const float* __restrict__ adst,
                               float* __restrict__ as1, float* __restrict__ ad1, int N) {
    int lane = threadIdx.x & 63;
    int w = threadIdx.x >> 6;
    int n = blockIdx.x * 4 + w;
    if (n >= N) return;
    const float* hrow = h1p + (size_t)n * HC;
    for (int h = 0; h < HEADS; ++h) {
        int c0 = h * CDIM + lane;
        float hv0 = hrow[c0], hv1 = hrow[c0 + 64];
        float ps = hv0 * asrc[c0] + hv1 * asrc[c0 + 64];
        float pd = hv0 * adst[c0] + hv1 * adst[c0 + 64];
        #pragma unroll
        for (int off = 32; off; off >>= 1) {
            ps += __shfl_xor(ps, off);
            pd += __shfl_xor(pd, off);
        }
        if (lane == 0) { as1[n * HEADS + h] = ps; ad1[n * HEADS + h] = pd; }
    }
}

// ---------------- attention scores, layer 2 (1 head) ----------------
__global__ void scores2_kernel(const float* __restrict__ h2p,
                               const float* __restrict__ asrc, const float* __restrict__ adst,
                               float* __restrict__ as2, float* __restrict__ ad2, int N) {
    int lane = threadIdx.x & 63;
    int w = threadIdx.x >> 6;
    int n = blockIdx.x * 4 + w;
    if (n >= N) return;
    const float* hrow = h2p + (size_t)n * CDIM;
    float hv0 = hrow[lane], hv1 = hrow[lane + 64];
    float ps = hv0 * asrc[lane] + hv1 * asrc[lane + 64];
    float pd = hv0 * adst[lane] + hv1 * adst[lane + 64];
    #pragma unroll
    for (int off = 32; off; off >>= 1) {
        ps += __shfl_xor(ps, off);
        pd += __shfl_xor(pd, off);
    }
    if (lane == 0) { as2[n] = ps; ad2[n] = pd; }
}

// ---------------- CSR build ----------------
__global__ void hist_kernel(const int* __restrict__ ei, int E, int N, unsigned* counts) {
    int e = blockIdx.x * 256 + threadIdx.x;
    int Et = E + N;
    if (e >= Et) return;
    int d = (e < E) ? ei[E + e] : (e - E);
    atomicAdd(&counts[d], 1u);
}

__global__ void scan_kernel(const unsigned* __restrict__ counts, unsigned* __restrict__ offsets, int n) {
    __shared__ unsigned part[1024];
    int t = threadIdx.x;
    int chunk = (n + 1023) / 1024;
    int lo = t * chunk, hi = min(lo + chunk, n);
    unsigned s = 0;
    for (int i = lo; i < hi; ++i) s += counts[i];
    part[t] = s;
    __syncthreads();
    for (int d = 1; d < 1024; d <<= 1) {
        unsigned v = (t >= d) ? part[t - d] : 0u;
        __syncthreads();
        part[t] += v;
        __syncthreads();
    }
    unsigned base = (t == 0) ? 0u : part[t - 1];
    for (int i = lo; i < hi; ++i) { offsets[i] = base; base += counts[i]; }
    if (t == 1023) offsets[n] = part[1023];
}

__global__ void scatter_kernel(const int* __restrict__ ei, int E, int N,
                               const unsigned* __restrict__ offsets, unsigned* cursor,
                               int* __restrict__ csr_src, int* __restrict__ csr_eid) {
    int e = blockIdx.x * 256 + threadIdx.x;
    int Et = E + N;
    if (e >= Et) return;
    int s, d;
    if (e < E) { s = ei[e]; d = ei[E + e]; } else { s = e - E; d = e - E; }
    unsigned pos = offsets[d] + atomicAdd(&cursor[d], 1u);
    csr_src[pos] = s;
    csr_eid[pos] = e;
}

// ---------------- segment softmax, layer 1: writes alpha1 into d_out ----------------
__global__ void softmax1_kernel(const unsigned* __restrict__ offsets,
                                const int* __restrict__ csr_src, const int* __restrict__ csr_eid,
                                const float* __restrict__ as1, const float* __restrict__ ad1,
                                float* __restrict__ alpha_out, int N) {
    int t = blockIdx.x * 256 + threadIdx.x;
    if (t >= N * HEADS) return;
    int n = t / HEADS, h = t % HEADS;
    unsigned p0 = offsets[n], p1 = offsets[n + 1];
    float adn = ad1[n * HEADS + h];
    float m = -INFINITY;
    for (unsigned p = p0; p < p1; ++p) {
        float e = as1[csr_src[p] * HEADS + h] + adn;
        e = (e >= 0.f) ? e : 0.2f * e;
        m = fmaxf(m, e);
    }
    float den = 0.f;
    for (unsigned p = p0; p < p1; ++p) {
        float e = as1[csr_src[p] * HEADS + h] + adn;
        e = (e >= 0.f) ? e : 0.2f * e;
        den += __expf(e - m);
    }
    float inv = 1.f / (den + 1e-16f);
    for (unsigned p = p0; p < p1; ++p) {
        float e = as1[csr_src[p] * HEADS + h] + adn;
        e = (e >= 0.f) ? e : 0.2f * e;
        alpha_out[(size_t)csr_eid[p] * HEADS + h] = __expf(e - m) * inv;
    }
}

// ---------------- segment softmax, layer 2 (alpha in CSR order) ----------------
__global__ void softmax2_kernel(const unsigned* __restrict__ offsets,
                                const int* __restrict__ csr_src,
                                const float* __restrict__ as2, const float* __restrict__ ad2,
                                float* __restrict__ alpha2, int N) {
    int n = blockIdx.x * 256 + threadIdx.x;
    if (n >= N) return;
    unsigned p0 = offsets[n], p1 = offsets[n + 1];
    float adn = ad2[n];
    float m = -INFINITY;
    for (unsigned p = p0; p < p1; ++p) {
        float e = as2[csr_src[p]] + adn;
        e = (e >= 0.f) ? e : 0.2f * e;
        m = fmaxf(m, e);
    }
    float den = 0.f;
    for (unsigned p = p0; p < p1; ++p) {
        float e = as2[csr_src[p]] + adn;
        e = (e >= 0.f) ? e : 0.2f * e;
        den += __expf(e - m);
    }
    float inv = 1.f / (den + 1e-16f);
    for (unsigned p = p0; p < p1; ++p) {
        float e = as2[csr_src[p]] + adn;
        e = (e >= 0.f) ? e : 0.2f * e;
        alpha2[p] = __expf(e - m) * inv;
    }
}

// ---------------- aggregation layer 1 + elu -> h1 (bf16): one block (256t) per node ----------------
__global__ void agg1_kernel(const unsigned* __restrict__ offsets,
                            const int* __restrict__ csr_src, const int* __restrict__ csr_eid,
                            const float* __restrict__ alpha_out, const float* __restrict__ h1p,
                            const float* __restrict__ b1, __bf16* __restrict__ h1b, int N) {
    __shared__ float a_lds[64 * HEADS];
    __shared__ int s_lds[64];
    int n = blockIdx.x;
    unsigned p0 = offsets[n], p1 = offsets[n + 1];
    int tid = threadIdx.x;
    float acc[5] = {0.f, 0.f, 0.f, 0.f, 0.f};
    for (unsigned base = p0; base < p1; base += 64) {
        int cnt = (int)min(64u, p1 - base);
        for (int idx = tid; idx < cnt * HEADS; idx += 256) {
            int j = idx / HEADS, h = idx % HEADS;
            a_lds[idx] = alpha_out[(size_t)csr_eid[base + j] * HEADS + h];
        }
        for (int idx = tid; idx < cnt; idx += 256) s_lds[idx] = csr_src[base + idx];
        __syncthreads();
        for (int j = 0; j < cnt; ++j) {
            const float* hrow = h1p + (size_t)s_lds[j] * HC;
            #pragma unroll
            for (int r = 0; r < 5; ++r) {
                int cc = tid + r * 256;
                acc[r] += hrow[cc] * a_lds[j * HEADS + (cc >> 7)];
            }
        }
        __syncthreads();
    }
    #pragma unroll
    for (int r = 0; r < 5; ++r) {
        int cc = tid + r * 256;
        float v = acc[r] + b1[cc];
        v = (v > 0.f) ? v : expm1f(v);
        h1b[(size_t)n * HC + cc] = (__bf16)v;
    }
}

// ---------------- aggregation layer 2 + elu: one block (128t) per node ----------------
__global__ void agg2_kernel(const unsigned* __restrict__ offsets,
                            const int* __restrict__ csr_src, const float* __restrict__ alpha2,
                            const float* __restrict__ h2p, const float* __restrict__ b2,
                            float* __restrict__ h2, int N) {
    int n = blockIdx.x;
    int c = threadIdx.x;
    unsigned p0 = offsets[n], p1 = offsets[n + 1];
    float acc = 0.f;
    for (unsigned p = p0; p < p1; ++p) {
        acc += h2p[(size_t)csr_src[p] * CDIM + c] * alpha2[p];
    }
    float v = acc + b2[c];
    h2[(size_t)n * CDIM + c] = (v > 0.f) ? v : expm1f(v);
}

// ---------------- pooling: monotone-uint atomicMax ----------------
__device__ __forceinline__ unsigned enc_f(float f) {
    unsigned b = __float_as_uint(f);
    return (b & 0x80000000u) ? ~b : (b | 0x80000000u);
}
__device__ __forceinline__ float dec_f(unsigned k) {
    return (k & 0x80000000u) ? __uint_as_float(k & 0x7FFFFFFFu) : __uint_as_float(~k);
}

__global__ void pool_kernel(const float* __restrict__ h2, const int* __restrict__ batch,
                            unsigned* __restrict__ pooled_u, int N) {
    int t = blockIdx.x * 256 + threadIdx.x;
    if (t >= N * CDIM) return;
    int n = t >> 7, c = t & 127;
    atomicMax(&pooled_u[batch[n] * CDIM + c], enc_f(h2[t]));
}

__global__ void pool_write_kernel(const unsigned* __restrict__ pooled_u, float* __restrict__ out) {
    int t = blockIdx.x * 256 + threadIdx.x;
    if (t < GRAPHS * CDIM) out[t] = dec_f(pooled_u[t]);
}

extern "C" void kernel_launch(void* const* d_in, const int* in_sizes, int n_in,
                              void* d_out, int out_size, void* d_ws, size_t ws_size,
                              hipStream_t stream) {
    const float* x     = (const float*)d_in[0];
    const int*   ei    = (const int*)d_in[1];
    const int*   batch = (const int*)d_in[2];
    const float* W1    = (const float*)d_in[3];
    const float* asrc1 = (const float*)d_in[4];
    const float* adst1 = (const float*)d_in[5];
    const float* b1    = (const float*)d_in[6];
    const float* W2    = (const float*)d_in[7];
    const float* asrc2 = (const float*)d_in[8];
    const float* adst2 = (const float*)d_in[9];
    const float* b2    = (const float*)d_in[10];
    float* out = (float*)d_out;

    const int N  = in_sizes[0] / FIN;
    const int E  = in_sizes[1] / 2;
    const int Et = E + N;

    char* w = (char*)d_ws;
    auto alloc = [&](size_t nbytes) {
        char* p = w;
        w += (nbytes + 255) & ~(size_t)255;
        return p;
    };
    float*  h1p  = (float*)alloc((size_t)N * HC * 4);
    __bf16* h1b  = (__bf16*)alloc((size_t)N * HC * 2);
    __bf16* W2t  = (__bf16*)alloc((size_t)CDIM * HC * 2);
    float*  h2p  = (float*)alloc((size_t)N * CDIM * 4);
    float*  h2   = (float*)alloc((size_t)N * CDIM * 4);
    float*  as1  = (float*)alloc((size_t)N * HEADS * 4);
    float*  ad1  = (float*)alloc((size_t)N * HEADS * 4);
    float*  as2  = (float*)alloc((size_t)N * 4);
    float*  ad2  = (float*)alloc((size_t)N * 4);
    float*  alpha2 = (float*)alloc((size_t)Et * 4);
    unsigned* counts  = (unsigned*)alloc((size_t)N * 4);
    unsigned* cursor  = (unsigned*)alloc((size_t)N * 4);
    unsigned* offsets = (unsigned*)alloc((size_t)(N + 1) * 4);
    int* csr_src = (int*)alloc((size_t)Et * 4);
    int* csr_eid = (int*)alloc((size_t)Et * 4);
    unsigned* pooled_u = (unsigned*)alloc((size_t)GRAPHS * CDIM * 4);

    float* alpha_out = out + GRAPHS * CDIM;  // alpha1 region of d_out

    init_kernel<<<(N + 255) / 256, 256, 0, stream>>>(counts, cursor, pooled_u, N);

    // layer-1 GEMM: [N,78] @ [78,1280] (fp32 vector ALU)
    gemm_kernel<64, 128, 26, 4, 8><<<dim3((N + 63) / 64, HC / 128), 256, 0, stream>>>(
        x, W1, h1p, N, HC, FIN);
    scores1_kernel<<<(N + 3) / 4, 256, 0, stream>>>(h1p, asrc1, adst1, as1, ad1, N);

    // CSR by dst
    hist_kernel<<<(Et + 255) / 256, 256, 0, stream>>>(ei, E, N, counts);
    scan_kernel<<<1, 1024, 0, stream>>>(counts, offsets, N);
    scatter_kernel<<<(Et + 255) / 256, 256, 0, stream>>>(ei, E, N, offsets, cursor, csr_src, csr_eid);

    softmax1_kernel<<<(N * HEADS + 255) / 256, 256, 0, stream>>>(
        offsets, csr_src, csr_eid, as1, ad1, alpha_out, N);
    agg1_kernel<<<N, 256, 0, stream>>>(offsets, csr_src, csr_eid, alpha_out, h1p, b1, h1b, N);

    // layer-2 GEMM: [N,1280] @ [1280,128] via bf16 MFMA
    w2t_kernel<<<(HC * CDIM + 255) / 256, 256, 0, stream>>>(W2, W2t);
    gemm2_mfma_kernel<<<dim3((N + 63) / 64, CDIM / 64), 256, 0, stream>>>(h1b, W2t, h2p, N);

    scores2_kernel<<<(N + 3) / 4, 256, 0, stream>>>(h2p, asrc2, adst2, as2, ad2, N);
    softmax2_kernel<<<(N + 255) / 256, 256, 0, stream>>>(offsets, csr_src, as2, ad2, alpha2, N);
    agg2_kernel<<<N, 128, 0, stream>>>(offsets, csr_src, alpha2, h2p, b2, h2, N);

    pool_kernel<<<(N * CDIM + 255) / 256, 256, 0, stream>>>(h2, batch, pooled_u, N);
    pool_write_kernel<<<(GRAPHS * CDIM + 255) / 256, 256, 0, stream>>>(pooled_u, out);
}

// Round 3
// 352.049 us; speedup vs baseline: 1.8984x; 1.1825x over previous
//
#include <hip/hip_runtime.h>
#include <hip/hip_bf16.h>

#define FIN 78
#define CDIM 128
#define HEADS 10
#define HC 1280
#define GRAPHS 64

typedef __bf16 bf16x8 __attribute__((ext_vector_type(8)));
typedef float f32x4 __attribute__((ext_vector_type(4)));

// ---------------- init ----------------
__global__ void init_kernel(unsigned* counts, unsigned* cursor, unsigned* pooled_u, int N) {
    int t = blockIdx.x * 256 + threadIdx.x;
    if (t < N) { counts[t] = 0u; cursor[t] = 0u; }
    if (t < GRAPHS * CDIM) pooled_u[t] = 0x007FFFFFu;  // enc(-inf)
}

// ---------------- layer-1 GEMM via bf16 MFMA: h1pb[M,1280] = bf16(x[M,78] @ W1[78,1280]) ----
// K=78 staged once, zero-padded to 96. Block 64x64, 4 waves 2x2.
__global__ __launch_bounds__(256) void gemm1_mfma_kernel(
        const float* __restrict__ x, const float* __restrict__ W1,
        __bf16* __restrict__ h1pb, int M) {
    __shared__ __align__(16) __bf16 Alds[64][104];   // [m][k], stride 104 elems (16B-aligned rows)
    __shared__ __align__(16) __bf16 Blds[64][104];   // [n][k]
    const int tid = threadIdx.x;
    const int wave = tid >> 6, lane = tid & 63;
    const int wr = wave >> 1, wc = wave & 1;
    const int m0 = blockIdx.x * 64;
    const int n0 = blockIdx.y * 64;
    const int fl = lane & 15;
    const int fh = lane >> 4;

    // stage A: x fp32 -> bf16, zero-pad k in [78,96)
    for (int idx = tid; idx < 64 * 96; idx += 256) {
        int m = idx / 96, k = idx % 96;
        int gm = m0 + m;
        float v = (gm < M && k < FIN) ? x[(size_t)gm * FIN + k] : 0.f;
        Alds[m][k] = (__bf16)v;
    }
    // stage B: W1[k][n] -> Blds[n][k], k-major loop for coalesced reads
    for (int idx = tid; idx < 96 * 64; idx += 256) {
        int k = idx / 64, n = idx % 64;
        float v = (k < FIN) ? W1[(size_t)k * HC + n0 + n] : 0.f;
        Blds[n][k] = (__bf16)v;
    }
    __syncthreads();

    f32x4 acc[2][2] = {};
    #pragma unroll
    for (int ks = 0; ks < 96; ks += 32) {
        bf16x8 a[2], b[2];
        #pragma unroll
        for (int t = 0; t < 2; ++t) {
            a[t] = *(const bf16x8*)&Alds[wr * 32 + t * 16 + fl][ks + fh * 8];
            b[t] = *(const bf16x8*)&Blds[wc * 32 + t * 16 + fl][ks + fh * 8];
        }
        #pragma unroll
        for (int i = 0; i < 2; ++i)
            #pragma unroll
            for (int j = 0; j < 2; ++j)
                acc[i][j] = __builtin_amdgcn_mfma_f32_16x16x32_bf16(a[i], b[j], acc[i][j], 0, 0, 0);
    }
    #pragma unroll
    for (int i = 0; i < 2; ++i)
        #pragma unroll
        for (int j = 0; j < 2; ++j)
            #pragma unroll
            for (int r = 0; r < 4; ++r) {
                int gm = m0 + wr * 32 + i * 16 + fh * 4 + r;
                if (gm < M) {
                    int gn = n0 + wc * 32 + j * 16 + fl;
                    h1pb[(size_t)gm * HC + gn] = (__bf16)acc[i][j][r];
                }
            }
}

// ---------------- W2 transpose + bf16 convert ----------------
__global__ void w2t_kernel(const float* __restrict__ W2, __bf16* __restrict__ W2t) {
    int t = blockIdx.x * 256 + threadIdx.x;
    if (t >= HC * CDIM) return;
    int k = t >> 7, n = t & 127;
    W2t[(size_t)n * HC + k] = (__bf16)W2[t];
}

// ---------------- layer-2 GEMM via bf16 MFMA ----------------
__global__ __launch_bounds__(256) void gemm2_mfma_kernel(
        const __bf16* __restrict__ A, const __bf16* __restrict__ Bt,
        float* __restrict__ C, int M) {
    constexpr int BK = 64;
    __shared__ __align__(16) __bf16 Alds[64][BK + 8];
    __shared__ __align__(16) __bf16 Blds[64][BK + 8];
    const int tid = threadIdx.x;
    const int wave = tid >> 6, lane = tid & 63;
    const int wr = wave >> 1, wc = wave & 1;
    const int m0 = blockIdx.x * 64;
    const int n0 = blockIdx.y * 64;

    const int kslot = (tid & 7) * 8;
    const int srow  = tid >> 3;

    const int fl = lane & 15;
    const int fh = lane >> 4;

    f32x4 acc[2][2] = {};

    for (int k0 = 0; k0 < HC; k0 += BK) {
        #pragma unroll
        for (int rp = 0; rp < 2; ++rp) {
            int r = srow + rp * 32;
            int gm = m0 + r;
            bf16x8 va = {};
            if (gm < M) va = *(const bf16x8*)(A + (size_t)gm * HC + k0 + kslot);
            *(bf16x8*)&Alds[r][kslot] = va;
            bf16x8 vb = *(const bf16x8*)(Bt + (size_t)(n0 + r) * HC + k0 + kslot);
            *(bf16x8*)&Blds[r][kslot] = vb;
        }
        __syncthreads();
        #pragma unroll
        for (int ks = 0; ks < BK; ks += 32) {
            bf16x8 a[2], b[2];
            #pragma unroll
            for (int t = 0; t < 2; ++t) {
                a[t] = *(const bf16x8*)&Alds[wr * 32 + t * 16 + fl][ks + fh * 8];
                b[t] = *(const bf16x8*)&Blds[wc * 32 + t * 16 + fl][ks + fh * 8];
            }
            #pragma unroll
            for (int i = 0; i < 2; ++i)
                #pragma unroll
                for (int j = 0; j < 2; ++j)
                    acc[i][j] = __builtin_amdgcn_mfma_f32_16x16x32_bf16(a[i], b[j], acc[i][j], 0, 0, 0);
        }
        __syncthreads();
    }
    #pragma unroll
    for (int i = 0; i < 2; ++i)
        #pragma unroll
        for (int j = 0; j < 2; ++j)
            #pragma unroll
            for (int r = 0; r < 4; ++r) {
                int gm = m0 + wr * 32 + i * 16 + fh * 4 + r;
                if (gm < M) {
                    int gn = n0 + wc * 32 + j * 16 + fl;
                    C[(size_t)gm * CDIM + gn] = acc[i][j][r];
                }
            }
}

// ---------------- attention scores, layer 1 (10 heads, bf16 h) ----------------
__global__ void scores1_kernel(const __bf16* __restrict__ h1pb,
                               const float* __restrict__ asrc, const float* __restrict__ adst,
                               float* __restrict__ as1, float* __restrict__ ad1, int N) {
    int lane = threadIdx.x & 63;
    int w = threadIdx.x >> 6;
    int n = blockIdx.x * 4 + w;
    if (n >= N) return;
    const __bf16* hrow = h1pb + (size_t)n * HC;
    for (int h = 0; h < HEADS; ++h) {
        int c0 = h * CDIM + lane;
        float hv0 = (float)hrow[c0], hv1 = (float)hrow[c0 + 64];
        float ps = hv0 * asrc[c0] + hv1 * asrc[c0 + 64];
        float pd = hv0 * adst[c0] + hv1 * adst[c0 + 64];
        #pragma unroll
        for (int off = 32; off; off >>= 1) {
            ps += __shfl_xor(ps, off);
            pd += __shfl_xor(pd, off);
        }
        if (lane == 0) { as1[n * HEADS + h] = ps; ad1[n * HEADS + h] = pd; }
    }
}

// ---------------- attention scores, layer 2 (1 head) ----------------
__global__ void scores2_kernel(const float* __restrict__ h2p,
                               const float* __restrict__ asrc, const float* __restrict__ adst,
                               float* __restrict__ as2, float* __restrict__ ad2, int N) {
    int lane = threadIdx.x & 63;
    int w = threadIdx.x >> 6;
    int n = blockIdx.x * 4 + w;
    if (n >= N) return;
    const float* hrow = h2p + (size_t)n * CDIM;
    float hv0 = hrow[lane], hv1 = hrow[lane + 64];
    float ps = hv0 * asrc[lane] + hv1 * asrc[lane + 64];
    float pd = hv0 * adst[lane] + hv1 * adst[lane + 64];
    #pragma unroll
    for (int off = 32; off; off >>= 1) {
        ps += __shfl_xor(ps, off);
        pd += __shfl_xor(pd, off);
    }
    if (lane == 0) { as2[n] = ps; ad2[n] = pd; }
}

// ---------------- CSR build ----------------
__global__ void hist_kernel(const int* __restrict__ ei, int E, int N, unsigned* counts) {
    int e = blockIdx.x * 256 + threadIdx.x;
    int Et = E + N;
    if (e >= Et) return;
    int d = (e < E) ? ei[E + e] : (e - E);
    atomicAdd(&counts[d], 1u);
}

__global__ void scan_kernel(const unsigned* __restrict__ counts, unsigned* __restrict__ offsets, int n) {
    __shared__ unsigned part[1024];
    int t = threadIdx.x;
    int chunk = (n + 1023) / 1024;
    int lo = t * chunk, hi = min(lo + chunk, n);
    unsigned s = 0;
    for (int i = lo; i < hi; ++i) s += counts[i];
    part[t] = s;
    __syncthreads();
    for (int d = 1; d < 1024; d <<= 1) {
        unsigned v = (t >= d) ? part[t - d] : 0u;
        __syncthreads();
        part[t] += v;
        __syncthreads();
    }
    unsigned base = (t == 0) ? 0u : part[t - 1];
    for (int i = lo; i < hi; ++i) { offsets[i] = base; base += counts[i]; }
    if (t == 1023) offsets[n] = part[1023];
}

__global__ void scatter_kernel(const int* __restrict__ ei, int E, int N,
                               const unsigned* __restrict__ offsets, unsigned* cursor,
                               int* __restrict__ csr_src, int* __restrict__ csr_eid) {
    int e = blockIdx.x * 256 + threadIdx.x;
    int Et = E + N;
    if (e >= Et) return;
    int s, d;
    if (e < E) { s = ei[e]; d = ei[E + e]; } else { s = e - E; d = e - E; }
    unsigned pos = offsets[d] + atomicAdd(&cursor[d], 1u);
    csr_src[pos] = s;
    csr_eid[pos] = e;
}

// ---------------- segment softmax, layer 1: writes alpha1 into d_out ----------------
__global__ void softmax1_kernel(const unsigned* __restrict__ offsets,
                                const int* __restrict__ csr_src, const int* __restrict__ csr_eid,
                                const float* __restrict__ as1, const float* __restrict__ ad1,
                                float* __restrict__ alpha_out, int N) {
    int t = blockIdx.x * 256 + threadIdx.x;
    if (t >= N * HEADS) return;
    int n = t / HEADS, h = t % HEADS;
    unsigned p0 = offsets[n], p1 = offsets[n + 1];
    float adn = ad1[n * HEADS + h];
    float m = -INFINITY;
    for (unsigned p = p0; p < p1; ++p) {
        float e = as1[csr_src[p] * HEADS + h] + adn;
        e = (e >= 0.f) ? e : 0.2f * e;
        m = fmaxf(m, e);
    }
    float den = 0.f;
    for (unsigned p = p0; p < p1; ++p) {
        float e = as1[csr_src[p] * HEADS + h] + adn;
        e = (e >= 0.f) ? e : 0.2f * e;
        den += __expf(e - m);
    }
    float inv = 1.f / (den + 1e-16f);
    for (unsigned p = p0; p < p1; ++p) {
        float e = as1[csr_src[p] * HEADS + h] + adn;
        e = (e >= 0.f) ? e : 0.2f * e;
        alpha_out[(size_t)csr_eid[p] * HEADS + h] = __expf(e - m) * inv;
    }
}

// ---------------- segment softmax, layer 2 (alpha in CSR order) ----------------
__global__ void softmax2_kernel(const unsigned* __restrict__ offsets,
                                const int* __restrict__ csr_src,
                                const float* __restrict__ as2, const float* __restrict__ ad2,
                                float* __restrict__ alpha2, int N) {
    int n = blockIdx.x * 256 + threadIdx.x;
    if (n >= N) return;
    unsigned p0 = offsets[n], p1 = offsets[n + 1];
    float adn = ad2[n];
    float m = -INFINITY;
    for (unsigned p = p0; p < p1; ++p) {
        float e = as2[csr_src[p]] + adn;
        e = (e >= 0.f) ? e : 0.2f * e;
        m = fmaxf(m, e);
    }
    float den = 0.f;
    for (unsigned p = p0; p < p1; ++p) {
        float e = as2[csr_src[p]] + adn;
        e = (e >= 0.f) ? e : 0.2f * e;
        den += __expf(e - m);
    }
    float inv = 1.f / (den + 1e-16f);
    for (unsigned p = p0; p < p1; ++p) {
        float e = as2[csr_src[p]] + adn;
        e = (e >= 0.f) ? e : 0.2f * e;
        alpha2[p] = __expf(e - m) * inv;
    }
}

// ---------------- aggregation layer 1 + elu -> h1b (bf16): one block (256t) per node ----
__global__ void agg1_kernel(const unsigned* __restrict__ offsets,
                            const int* __restrict__ csr_src, const int* __restrict__ csr_eid,
                            const float* __restrict__ alpha_out, const __bf16* __restrict__ h1pb,
                            const float* __restrict__ b1, __bf16* __restrict__ h1b, int N) {
    __shared__ float a_lds[64 * HEADS];
    __shared__ int s_lds[64];
    int n = blockIdx.x;
    unsigned p0 = offsets[n], p1 = offsets[n + 1];
    int tid = threadIdx.x;
    float acc[5] = {0.f, 0.f, 0.f, 0.f, 0.f};
    for (unsigned base = p0; base < p1; base += 64) {
        int cnt = (int)min(64u, p1 - base);
        for (int idx = tid; idx < cnt * HEADS; idx += 256) {
            int j = idx / HEADS, h = idx % HEADS;
            a_lds[idx] = alpha_out[(size_t)csr_eid[base + j] * HEADS + h];
        }
        for (int idx = tid; idx < cnt; idx += 256) s_lds[idx] = csr_src[base + idx];
        __syncthreads();
        for (int j = 0; j < cnt; ++j) {
            const __bf16* hrow = h1pb + (size_t)s_lds[j] * HC;
            #pragma unroll
            for (int r = 0; r < 5; ++r) {
                int cc = tid + r * 256;
                acc[r] += (float)hrow[cc] * a_lds[j * HEADS + (cc >> 7)];
            }
        }
        __syncthreads();
    }
    #pragma unroll
    for (int r = 0; r < 5; ++r) {
        int cc = tid + r * 256;
        float v = acc[r] + b1[cc];
        v = (v > 0.f) ? v : expm1f(v);
        h1b[(size_t)n * HC + cc] = (__bf16)v;
    }
}

// ---------------- aggregation layer 2 + elu: one block (128t) per node ----------------
__global__ void agg2_kernel(const unsigned* __restrict__ offsets,
                            const int* __restrict__ csr_src, const float* __restrict__ alpha2,
                            const float* __restrict__ h2p, const float* __restrict__ b2,
                            float* __restrict__ h2, int N) {
    int n = blockIdx.x;
    int c = threadIdx.x;
    unsigned p0 = offsets[n], p1 = offsets[n + 1];
    float acc = 0.f;
    for (unsigned p = p0; p < p1; ++p) {
        acc += h2p[(size_t)csr_src[p] * CDIM + c] * alpha2[p];
    }
    float v = acc + b2[c];
    h2[(size_t)n * CDIM + c] = (v > 0.f) ? v : expm1f(v);
}

// ---------------- pooling: monotone-uint atomicMax ----------------
__device__ __forceinline__ unsigned enc_f(float f) {
    unsigned b = __float_as_uint(f);
    return (b & 0x80000000u) ? ~b : (b | 0x80000000u);
}
__device__ __forceinline__ float dec_f(unsigned k) {
    return (k & 0x80000000u) ? __uint_as_float(k & 0x7FFFFFFFu) : __uint_as_float(~k);
}

__global__ void pool_kernel(const float* __restrict__ h2, const int* __restrict__ batch,
                            unsigned* __restrict__ pooled_u, int N) {
    int t = blockIdx.x * 256 + threadIdx.x;
    if (t >= N * CDIM) return;
    int n = t >> 7, c = t & 127;
    atomicMax(&pooled_u[batch[n] * CDIM + c], enc_f(h2[t]));
}

__global__ void pool_write_kernel(const unsigned* __restrict__ pooled_u, float* __restrict__ out) {
    int t = blockIdx.x * 256 + threadIdx.x;
    if (t < GRAPHS * CDIM) out[t] = dec_f(pooled_u[t]);
}

extern "C" void kernel_launch(void* const* d_in, const int* in_sizes, int n_in,
                              void* d_out, int out_size, void* d_ws, size_t ws_size,
                              hipStream_t stream) {
    const float* x     = (const float*)d_in[0];
    const int*   ei    = (const int*)d_in[1];
    const int*   batch = (const int*)d_in[2];
    const float* W1    = (const float*)d_in[3];
    const float* asrc1 = (const float*)d_in[4];
    const float* adst1 = (const float*)d_in[5];
    const float* b1    = (const float*)d_in[6];
    const float* W2    = (const float*)d_in[7];
    const float* asrc2 = (const float*)d_in[8];
    const float* adst2 = (const float*)d_in[9];
    const float* b2    = (const float*)d_in[10];
    float* out = (float*)d_out;

    const int N  = in_sizes[0] / FIN;
    const int E  = in_sizes[1] / 2;
    const int Et = E + N;

    char* w = (char*)d_ws;
    auto alloc = [&](size_t nbytes) {
        char* p = w;
        w += (nbytes + 255) & ~(size_t)255;
        return p;
    };
    __bf16* h1pb = (__bf16*)alloc((size_t)N * HC * 2);   // pre-aggregation h (bf16)
    __bf16* h1b  = (__bf16*)alloc((size_t)N * HC * 2);   // post-elu h1 (bf16, GEMM2 input)
    __bf16* W2t  = (__bf16*)alloc((size_t)CDIM * HC * 2);
    float*  h2p  = (float*)alloc((size_t)N * CDIM * 4);
    float*  h2   = (float*)alloc((size_t)N * CDIM * 4);
    float*  as1  = (float*)alloc((size_t)N * HEADS * 4);
    float*  ad1  = (float*)alloc((size_t)N * HEADS * 4);
    float*  as2  = (float*)alloc((size_t)N * 4);
    float*  ad2  = (float*)alloc((size_t)N * 4);
    float*  alpha2 = (float*)alloc((size_t)Et * 4);
    unsigned* counts  = (unsigned*)alloc((size_t)N * 4);
    unsigned* cursor  = (unsigned*)alloc((size_t)N * 4);
    unsigned* offsets = (unsigned*)alloc((size_t)(N + 1) * 4);
    int* csr_src = (int*)alloc((size_t)Et * 4);
    int* csr_eid = (int*)alloc((size_t)Et * 4);
    unsigned* pooled_u = (unsigned*)alloc((size_t)GRAPHS * CDIM * 4);

    float* alpha_out = out + GRAPHS * CDIM;  // alpha1 region of d_out

    init_kernel<<<(N + 255) / 256, 256, 0, stream>>>(counts, cursor, pooled_u, N);

    // layer-1 GEMM: [N,78] @ [78,1280] via bf16 MFMA -> h1pb (bf16)
    gemm1_mfma_kernel<<<dim3((N + 63) / 64, HC / 64), 256, 0, stream>>>(x, W1, h1pb, N);
    scores1_kernel<<<(N + 3) / 4, 256, 0, stream>>>(h1pb, asrc1, adst1, as1, ad1, N);

    // CSR by dst
    hist_kernel<<<(Et + 255) / 256, 256, 0, stream>>>(ei, E, N, counts);
    scan_kernel<<<1, 1024, 0, stream>>>(counts, offsets, N);
    scatter_kernel<<<(Et + 255) / 256, 256, 0, stream>>>(ei, E, N, offsets, cursor, csr_src, csr_eid);

    softmax1_kernel<<<(N * HEADS + 255) / 256, 256, 0, stream>>>(
        offsets, csr_src, csr_eid, as1, ad1, alpha_out, N);
    agg1_kernel<<<N, 256, 0, stream>>>(offsets, csr_src, csr_eid, alpha_out, h1pb, b1, h1b, N);

    // layer-2 GEMM: [N,1280] @ [1280,128] via bf16 MFMA
    w2t_kernel<<<(HC * CDIM + 255) / 256, 256, 0, stream>>>(W2, W2t);
    gemm2_mfma_kernel<<<dim3((N + 63) / 64, CDIM / 64), 256, 0, stream>>>(h1b, W2t, h2p, N);

    scores2_kernel<<<(N + 3) / 4, 256, 0, stream>>>(h2p, asrc2, adst2, as2, ad2, N);
    softmax2_kernel<<<(N + 255) / 256, 256, 0, stream>>>(offsets, csr_src, as2, ad2, alpha2, N);
    agg2_kernel<<<N, 128, 0, stream>>>(offsets, csr_src, alpha2, h2p, b2, h2, N);

    pool_kernel<<<(N * CDIM + 255) / 256, 256, 0, stream>>>(h2, batch, pooled_u, N);
    pool_write_kernel<<<(GRAPHS * CDIM + 255) / 256, 256, 0, stream>>>(pooled_u, out);
}